// Round 8
// baseline (670.892 us; speedup 1.0000x reference)
//
#include <hip/hip_runtime.h>
#include <hip/hip_bf16.h>

// ToyMDNN on MI355X — round 8: restore pass margin (r7 failed by 1.5 ulp).
//  * out1 kept fp32, written IN-PLACE into h ([M][128]); ff_raw fp32 into the
//    dead qbuf+kbuf region -> removes the two output-adjacent bf16 roundings.
//  * fuse2 runs fp32 on t1/ff and writes h_next in-place over t1.
//  * everything else = round 7 (head-major q/k/v, direct B-frag GEMMs,
//    fused attn+LN, bit-packed mask).
// N=1024 S=128 D=128 H=4 C=32 L=2. GEMM biases cancel through batch-norm.

typedef __attribute__((ext_vector_type(8))) short short8v;
typedef __attribute__((ext_vector_type(16))) float f32x16;

#define NBATCH 1024
#define SEQ    128
#define DIM    128
#define NLAYER 2
#define MTOT   (NBATCH*SEQ)
#define EPSF   1e-5f
#define INV_M  (1.0f/131072.0f)
#define HM32   ((long)MTOT * 32)     // head-major per-head region (elements)

__device__ __forceinline__ float bf2f(ushort s) {
  return __uint_as_float(((uint)s) << 16);
}
__device__ __forceinline__ ushort f2bf(float f) {
  uint u = __float_as_uint(f);
  return (ushort)((u + 0x7FFFu + ((u >> 16) & 1u)) >> 16);
}

struct WPtrs { const float* p[11]; };

// ---------------------------------------------------------------------------
// One-time: 11 weight matrices fp32 -> bf16 packed in B-fragment order:
// dst[m*16384 + kc*1024 + nt*256 + ln*8 + i] = W[nt*32+ln][kc*8+i].
// ---------------------------------------------------------------------------
__global__ __launch_bounds__(256) void prep_w(WPtrs wp, ushort* __restrict__ dst)
{
  const int gid = blockIdx.x * 256 + threadIdx.x;   // 88*256 = 11*2048
  const int m = gid >> 11;
  const int rem = gid & 2047;
  const int j = rem >> 4, kc = rem & 15;
  const float* src = wp.p[m];
  float4 a = *(const float4*)(src + j * DIM + kc * 8);
  float4 b = *(const float4*)(src + j * DIM + kc * 8 + 4);
  short8v v;
  v[0] = (short)f2bf(a.x); v[1] = (short)f2bf(a.y);
  v[2] = (short)f2bf(a.z); v[3] = (short)f2bf(a.w);
  v[4] = (short)f2bf(b.x); v[5] = (short)f2bf(b.y);
  v[6] = (short)f2bf(b.z); v[7] = (short)f2bf(b.w);
  const int nt = j >> 5, ln = j & 31;
  *(short8v*)(dst + m * 16384 + kc * 1024 + nt * 256 + ln * 8) = v;
}

// ---------------------------------------------------------------------------
// One-time: pack 0/1 fp32 mask rows into 128-bit rows (uint4).
// ---------------------------------------------------------------------------
__global__ __launch_bounds__(256) void pack_mask(
    const float* __restrict__ mask, uint4* __restrict__ mb)
{
  const int lane = threadIdx.x & 63;
  const int wv   = (blockIdx.x * 256 + threadIdx.x) >> 6;
  const int NW   = gridDim.x * 4;
  for (int row = wv; row < MTOT; row += NW) {
    const float a = mask[(long)row * SEQ + lane];
    const float b = mask[(long)row * SEQ + 64 + lane];
    const unsigned long long lo = __ballot(a != 0.f);
    const unsigned long long hi = __ballot(b != 0.f);
    if (lane == 0) {
      uint4 w;
      w.x = (uint)lo; w.y = (uint)(lo >> 32);
      w.z = (uint)hi; w.w = (uint)(hi >> 32);
      mb[row] = w;
    }
  }
}

// ---------------------------------------------------------------------------
// Single GEMM: out[m][j] = sum_k A[m][k]*W[j][k] + column stats.
// Grid 1024. B-frags direct from packed global W.
// ---------------------------------------------------------------------------
template<bool ABF16, bool OBF16>
__global__ __launch_bounds__(256, 3) void gemm_one(
    const void* __restrict__ Ap, const ushort* __restrict__ Wm,
    void* __restrict__ outp, float* __restrict__ stats)
{
  __shared__ float csum[128], csq[128];
  const int tid = threadIdx.x;
  const int lane = tid & 63, wid = tid >> 6;
  const int hi = lane >> 5, ln = lane & 31;
  const long m0 = (long)blockIdx.x * 128;
  const long arow = m0 + wid * 32 + ln;

  if (tid < 128) { csum[tid] = 0.f; csq[tid] = 0.f; }

  short8v afr[8];
  if constexpr (ABF16) {
    const ushort* ar = (const ushort*)Ap + arow * DIM + hi * 8;
#pragma unroll
    for (int kt = 0; kt < 8; ++kt) afr[kt] = *(const short8v*)(ar + kt * 16);
  } else {
    const float* ar = (const float*)Ap + arow * DIM + hi * 8;
#pragma unroll
    for (int kt = 0; kt < 8; ++kt) {
      float4 a0 = *(const float4*)(ar + kt * 16);
      float4 a1 = *(const float4*)(ar + kt * 16 + 4);
      short8v v;
      v[0] = (short)f2bf(a0.x); v[1] = (short)f2bf(a0.y);
      v[2] = (short)f2bf(a0.z); v[3] = (short)f2bf(a0.w);
      v[4] = (short)f2bf(a1.x); v[5] = (short)f2bf(a1.y);
      v[6] = (short)f2bf(a1.z); v[7] = (short)f2bf(a1.w);
      afr[kt] = v;
    }
  }

  f32x16 acc[4];
#pragma unroll
  for (int nt = 0; nt < 4; ++nt)
#pragma unroll
    for (int r = 0; r < 16; ++r) acc[nt][r] = 0.f;

#pragma unroll
  for (int kt = 0; kt < 8; ++kt) {
    const ushort* wb = Wm + (kt * 2 + hi) * 1024 + ln * 8;
#pragma unroll
    for (int nt = 0; nt < 4; ++nt) {
      short8v b = *(const short8v*)(wb + nt * 256);
      acc[nt] = __builtin_amdgcn_mfma_f32_32x32x16_bf16(afr[kt], b, acc[nt], 0, 0, 0);
    }
  }

  float ps[4], pq[4];
#pragma unroll
  for (int nt = 0; nt < 4; ++nt) { ps[nt] = 0.f; pq[nt] = 0.f; }
#pragma unroll
  for (int nt = 0; nt < 4; ++nt) {
    const int col = nt * 32 + ln;
#pragma unroll
    for (int r = 0; r < 16; ++r) {
      const float v = acc[nt][r];
      ps[nt] += v; pq[nt] += v * v;
      const long row = m0 + wid * 32 + (r & 3) + 8 * (r >> 2) + 4 * hi;
      if constexpr (OBF16) ((ushort*)outp)[row * DIM + col] = f2bf(v);
      else                 ((float*)outp)[row * DIM + col] = v;
    }
  }
#pragma unroll
  for (int nt = 0; nt < 4; ++nt) {
    ps[nt] += __shfl_xor(ps[nt], 32);
    pq[nt] += __shfl_xor(pq[nt], 32);
  }
  __syncthreads();
  if (hi == 0) {
#pragma unroll
    for (int nt = 0; nt < 4; ++nt) {
      atomicAdd(&csum[nt * 32 + ln], ps[nt]);
      atomicAdd(&csq[nt * 32 + ln], pq[nt]);
    }
  }
  __syncthreads();
  if (tid < 128) {
    atomicAdd(&stats[tid],       csum[tid]);
    atomicAdd(&stats[128 + tid], csq[tid]);
  }
}

// ---------------------------------------------------------------------------
// Fused Q/K/V/SKIP GEMM. A (fp32 h) read once; 4 weight matrices (offsets
// 0,1,2,4 from wbase) loaded as direct B-frags. q/k/v written HEAD-MAJOR
// bf16; skip written [M][128] bf16.
// ---------------------------------------------------------------------------
__global__ __launch_bounds__(256, 2) void gemm_qkvs(
    const float* __restrict__ A, const ushort* __restrict__ wbase,
    ushort* __restrict__ o0, ushort* __restrict__ o1,
    ushort* __restrict__ o2, ushort* __restrict__ o3,
    float* __restrict__ st0, float* __restrict__ st1,
    float* __restrict__ st2, float* __restrict__ st3)
{
  __shared__ float csum[128], csq[128];
  const int tid = threadIdx.x;
  const int lane = tid & 63, wid = tid >> 6;
  const int hi = lane >> 5, ln = lane & 31;
  const long m0 = (long)blockIdx.x * 128;
  const long arow = m0 + wid * 32 + ln;

  if (tid < 128) { csum[tid] = 0.f; csq[tid] = 0.f; }

  short8v afr[8];
  {
    const float* ar = A + arow * DIM + hi * 8;
#pragma unroll
    for (int kt = 0; kt < 8; ++kt) {
      float4 a0 = *(const float4*)(ar + kt * 16);
      float4 a1 = *(const float4*)(ar + kt * 16 + 4);
      short8v v;
      v[0] = (short)f2bf(a0.x); v[1] = (short)f2bf(a0.y);
      v[2] = (short)f2bf(a0.z); v[3] = (short)f2bf(a0.w);
      v[4] = (short)f2bf(a1.x); v[5] = (short)f2bf(a1.y);
      v[6] = (short)f2bf(a1.z); v[7] = (short)f2bf(a1.w);
      afr[kt] = v;
    }
  }

  float ps[4][4], pq[4][4];
#pragma unroll
  for (int w = 0; w < 4; ++w)
#pragma unroll
    for (int nt = 0; nt < 4; ++nt) { ps[w][nt] = 0.f; pq[w][nt] = 0.f; }

#pragma unroll
  for (int w = 0; w < 4; ++w) {
    const ushort* Wm = wbase + ((w < 3) ? w : 4) * 16384;

    f32x16 acc[4];
#pragma unroll
    for (int nt = 0; nt < 4; ++nt)
#pragma unroll
      for (int r = 0; r < 16; ++r) acc[nt][r] = 0.f;
#pragma unroll
    for (int kt = 0; kt < 8; ++kt) {
      const ushort* wb = Wm + (kt * 2 + hi) * 1024 + ln * 8;
#pragma unroll
      for (int nt = 0; nt < 4; ++nt) {
        short8v b = *(const short8v*)(wb + nt * 256);
        acc[nt] = __builtin_amdgcn_mfma_f32_32x32x16_bf16(afr[kt], b, acc[nt], 0, 0, 0);
      }
    }

    ushort* outp = (w == 0) ? o0 : (w == 1) ? o1 : (w == 2) ? o2 : o3;
#pragma unroll
    for (int nt = 0; nt < 4; ++nt) {
#pragma unroll
      for (int r = 0; r < 16; ++r) {
        const float v = acc[nt][r];
        ps[w][nt] += v; pq[w][nt] += v * v;
        const long row = m0 + wid * 32 + (r & 3) + 8 * (r >> 2) + 4 * hi;
        if (w < 3) outp[(long)nt * HM32 + row * 32 + ln] = f2bf(v);      // head-major
        else       outp[row * DIM + nt * 32 + ln] = f2bf(v);             // [M][128]
      }
    }
  }

  __syncthreads();
#pragma unroll
  for (int w = 0; w < 4; ++w) {
    float* st = (w == 0) ? st0 : (w == 1) ? st1 : (w == 2) ? st2 : st3;
    float lps[4], lpq[4];
#pragma unroll
    for (int nt = 0; nt < 4; ++nt) {
      lps[nt] = ps[w][nt] + __shfl_xor(ps[w][nt], 32);
      lpq[nt] = pq[w][nt] + __shfl_xor(pq[w][nt], 32);
    }
    if (hi == 0) {
#pragma unroll
      for (int nt = 0; nt < 4; ++nt) {
        atomicAdd(&csum[nt * 32 + ln], lps[nt]);
        atomicAdd(&csq[nt * 32 + ln],  lpq[nt]);
      }
    }
    __syncthreads();
    if (tid < 128) {
      atomicAdd(&st[tid],       csum[tid]);
      atomicAdd(&st[128 + tid], csq[tid]);
      csum[tid] = 0.f; csq[tid] = 0.f;
    }
    __syncthreads();
  }
}

// ---------------------------------------------------------------------------
// In-place BN apply for h (fp32).
// ---------------------------------------------------------------------------
__global__ __launch_bounds__(256) void bn_apply(
    float* __restrict__ x, const float* __restrict__ st,
    const float* __restrict__ g, const float* __restrict__ b)
{
  __shared__ float sc[128], bi[128];
  const int tid = threadIdx.x;
  if (tid < 128) {
    float mean = st[tid] * INV_M;
    float var  = st[128 + tid] * INV_M - mean * mean;
    float s = rsqrtf(var + EPSF) * g[tid];
    sc[tid] = s;
    bi[tid] = b[tid] - mean * s;
  }
  __syncthreads();
  const long total4 = (long)MTOT * DIM / 4;
  for (long i = (long)blockIdx.x * 256 + tid; i < total4; i += (long)gridDim.x * 256) {
    float4 vv = ((const float4*)x)[i];
    const int c = (int)((i * 4) & 127);
    vv.x = vv.x * sc[c + 0] + bi[c + 0];
    vv.y = vv.y * sc[c + 1] + bi[c + 1];
    vv.z = vv.z * sc[c + 2] + bi[c + 2];
    vv.w = vv.w * sc[c + 3] + bi[c + 3];
    ((float4*)x)[i] = vv;
  }
}

// ---------------------------------------------------------------------------
// Attention + fused LN(agg+h). One block per n; wave = head.
// S^T = mfma(K,Q) -> in-lane softmax; PV from D-regs; V BN folded via
// sum(P)=1; y = vs*o+vb0 + h (fp32); LN across waves via LDS reduce;
// out1 written FP32 IN-PLACE over h ([M][128]) — each (row,col) is read once
// by the same lane that writes it, rows block-disjoint -> race-free.
// ---------------------------------------------------------------------------
__global__ __launch_bounds__(256, 4) void attn_ln(
    const ushort* __restrict__ q, const ushort* __restrict__ k_in,
    const ushort* __restrict__ v_in,
    float* hbuf,                      // h in, out1 out (aliased on purpose)
    const uint4* __restrict__ mb,
    const float* __restrict__ qst, const float* __restrict__ kst, const float* __restrict__ vst,
    const float* __restrict__ qg, const float* __restrict__ qbb,
    const float* __restrict__ kg, const float* __restrict__ kbb,
    const float* __restrict__ vg, const float* __restrict__ vbb,
    const float* __restrict__ lng, const float* __restrict__ lnb)
{
  __shared__ ushort Vp[128 * 136];          // [c_global][slot(t)]
  __shared__ float qsc[128], qbi[128], ksc[128], kbi[128];
  __shared__ float reds[32][4], redq[32][4];
  __shared__ float2 rmv[32];

  const int tid = threadIdx.x;
  const int lane = tid & 63, hh = tid >> 6;
  const int hi = lane >> 5, ln = lane & 31;
  const int n = blockIdx.x;
  const long nb = (long)n * SEQ;            // global row base
  const long hbase = (long)hh * HM32 + nb * 32;

  if (tid < 128) {
    const int c = tid;
    float m, v, s;
    m = qst[c] * INV_M; v = qst[128 + c] * INV_M - m * m;
    s = rsqrtf(v + EPSF) * qg[c];  qsc[c] = s; qbi[c] = qbb[c] - m * s;
    m = kst[c] * INV_M; v = kst[128 + c] * INV_M - m * m;
    s = rsqrtf(v + EPSF) * kg[c];  ksc[c] = s; kbi[c] = kbb[c] - m * s;
  }
  const int cg = hh * 32 + ln;              // global output column
  float vs, vb0;
  {
    float m = vst[cg] * INV_M;
    float v = vst[128 + cg] * INV_M - m * m;
    vs = rsqrtf(v + EPSF) * vg[cg];
    vb0 = vbb[cg] - m * vs;
  }
  const float lgc = lng[cg], lbc = lnb[cg];

  // stage own head's V slice (dense 8KB) into permuted slots
#pragma unroll
  for (int it = 0; it < 8; ++it) {
    const int t = it * 16 + (lane >> 2);
    const int c0 = (lane & 3) * 8;
    short8v vv = *(const short8v*)(v_in + hbase + (long)t * 32 + c0);
    const int tl = t & 31;
    const int kt = tl >> 4;
    const int rem = tl & 15;
    const int slot = (t & 96) + (kt << 4) + ((rem >> 2) & 1) * 8 + ((rem & 3) | (((rem >> 3) & 1) << 2));
#pragma unroll
    for (int i = 0; i < 8; ++i) Vp[(hh * 32 + c0 + i) * 136 + slot] = (ushort)vv[i];
  }
  __syncthreads();

  // normalized K fragments, cached for all row-tiles
  short8v kfr[4][2];
#pragma unroll
  for (int nt = 0; nt < 4; ++nt)
#pragma unroll
    for (int kt = 0; kt < 2; ++kt) {
      short8v raw = *(const short8v*)(k_in + hbase + (long)(nt * 32 + ln) * 32 + kt * 16 + hi * 8);
      short8v f;
#pragma unroll
      for (int i = 0; i < 8; ++i) {
        const int c = hh * 32 + kt * 16 + hi * 8 + i;
        f[i] = (short)f2bf(bf2f((ushort)raw[i]) * ksc[c] + kbi[c]);
      }
      kfr[nt][kt] = f;
    }

  for (int mt = 0; mt < 4; ++mt) {
    // normalized Q fragments (B operand): col s = mt*32+ln
    short8v qfr[2];
#pragma unroll
    for (int kt = 0; kt < 2; ++kt) {
      short8v raw = *(const short8v*)(q + hbase + (long)(mt * 32 + ln) * 32 + kt * 16 + hi * 8);
      short8v f;
#pragma unroll
      for (int i = 0; i < 8; ++i) {
        const int c = hh * 32 + kt * 16 + hi * 8 + i;
        f[i] = (short)f2bf(bf2f((ushort)raw[i]) * qsc[c] + qbi[c]);
      }
      qfr[kt] = f;
    }

    f32x16 st[4];
#pragma unroll
    for (int nt = 0; nt < 4; ++nt)
#pragma unroll
      for (int r = 0; r < 16; ++r) st[nt][r] = 0.f;
#pragma unroll
    for (int nt = 0; nt < 4; ++nt) {
      st[nt] = __builtin_amdgcn_mfma_f32_32x32x16_bf16(kfr[nt][0], qfr[0], st[nt], 0, 0, 0);
      st[nt] = __builtin_amdgcn_mfma_f32_32x32x16_bf16(kfr[nt][1], qfr[1], st[nt], 0, 0, 0);
    }

    // mask + in-lane softmax (softmax(alpha*mask) semantics)
    const uint4 bw = mb[nb + mt * 32 + ln];
    float mx = -1e30f;
#pragma unroll
    for (int nt = 0; nt < 4; ++nt) {
      const uint word = (nt == 0) ? bw.x : (nt == 1) ? bw.y : (nt == 2) ? bw.z : bw.w;
#pragma unroll
      for (int r = 0; r < 16; ++r) {
        const int crow = (r & 3) + 8 * (r >> 2) + 4 * hi;
        st[nt][r] = ((word >> crow) & 1u) ? st[nt][r] : 0.f;
        mx = fmaxf(mx, st[nt][r]);
      }
    }
    mx = fmaxf(mx, __shfl_xor(mx, 32));
    float sum = 0.f;
#pragma unroll
    for (int nt = 0; nt < 4; ++nt)
#pragma unroll
      for (int r = 0; r < 16; ++r) {
        const float e = __expf(st[nt][r] - mx);
        st[nt][r] = e;
        sum += e;
      }
    sum += __shfl_xor(sum, 32);
    const float inv = 1.f / sum;

    // O = P · V_raw
    f32x16 o;
#pragma unroll
    for (int r = 0; r < 16; ++r) o[r] = 0.f;
#pragma unroll
    for (int nt = 0; nt < 4; ++nt) {
#pragma unroll
      for (int kt = 0; kt < 2; ++kt) {
        short8v pa;
#pragma unroll
        for (int j = 0; j < 8; ++j) pa[j] = (short)f2bf(st[nt][kt * 8 + j] * inv);
        short8v vb = *(const short8v*)&Vp[(long)cg * 136 + nt * 32 + kt * 16 + hi * 8];
        o = __builtin_amdgcn_mfma_f32_32x32x16_bf16(pa, vb, o, 0, 0, 0);
      }
    }

    // y = BN_v-folded agg + h  (fp32; h read once per (row,col) by the
    // same lane that overwrites it below)
    float yv[16];
#pragma unroll
    for (int r = 0; r < 16; ++r) {
      const int sl = (r & 3) + 8 * (r >> 2) + 4 * hi;
      const float hval = hbuf[(nb + mt * 32 + sl) * DIM + cg];
      yv[r] = vs * o[r] + vb0 + hval;
    }

    // LN across full row: intra-half butterfly + cross-wave LDS reduce
#pragma unroll
    for (int r = 0; r < 16; ++r) {
      float s = yv[r], q2 = yv[r] * yv[r];
      s += __shfl_xor(s, 1);  q2 += __shfl_xor(q2, 1);
      s += __shfl_xor(s, 2);  q2 += __shfl_xor(q2, 2);
      s += __shfl_xor(s, 4);  q2 += __shfl_xor(q2, 4);
      s += __shfl_xor(s, 8);  q2 += __shfl_xor(q2, 8);
      s += __shfl_xor(s, 16); q2 += __shfl_xor(q2, 16);
      if (ln == 0) {
        const int sl = (r & 3) + 8 * (r >> 2) + 4 * hi;
        reds[sl][hh] = s; redq[sl][hh] = q2;
      }
    }
    __syncthreads();
    if (tid < 32) {
      const float s  = reds[tid][0] + reds[tid][1] + reds[tid][2] + reds[tid][3];
      const float q2 = redq[tid][0] + redq[tid][1] + redq[tid][2] + redq[tid][3];
      const float mean = s * (1.f / 128.f);
      const float var  = q2 * (1.f / 128.f) - mean * mean;
      rmv[tid] = make_float2(mean, rsqrtf(var + EPSF));
    }
    __syncthreads();
    // out1 fp32 in-place over h
#pragma unroll
    for (int r = 0; r < 16; ++r) {
      const int sl = (r & 3) + 8 * (r >> 2) + 4 * hi;
      const float2 mr = rmv[sl];
      hbuf[(nb + mt * 32 + sl) * DIM + cg] = (yv[r] - mr.x) * mr.y * lgc + lbc;
    }
  }
}

// ---------------------------------------------------------------------------
// h_new = LN(out1 + BN_ff(ff_raw)) + BN_skip(skip_raw).
// t1 (out1) fp32 [M][128]; ffr fp32 [M][128]; skr bf16 [M][128].
// Non-final: out == t1 (in-place; each element read once then written by the
// same lane). FINAL: rows m=n*S compact to (N,128) -> d_out.
// ---------------------------------------------------------------------------
template <bool FINAL>
__global__ __launch_bounds__(256) void fuse2_k(
    const float* t1, const float* __restrict__ ffr, const ushort* __restrict__ skr,
    const float* __restrict__ fst, const float* __restrict__ sst,
    const float* __restrict__ fg, const float* __restrict__ fb,
    const float* __restrict__ sg, const float* __restrict__ sb,
    const float* __restrict__ lg, const float* __restrict__ lb,
    float* out)
{
  const int lane = threadIdx.x & 63;
  const int c = lane * 2;
  float fs0, fbias0, fs1, fbias1, ss0, sbias0, ss1, sbias1;
  {
    float m0 = fst[c] * INV_M;
    float v0 = fst[128 + c] * INV_M - m0 * m0;
    fs0 = rsqrtf(v0 + EPSF) * fg[c];       fbias0 = fb[c] - m0 * fs0;
    float m1 = fst[c + 1] * INV_M;
    float v1 = fst[128 + c + 1] * INV_M - m1 * m1;
    fs1 = rsqrtf(v1 + EPSF) * fg[c + 1];   fbias1 = fb[c + 1] - m1 * fs1;
    float n0 = sst[c] * INV_M;
    float w0 = sst[128 + c] * INV_M - n0 * n0;
    ss0 = rsqrtf(w0 + EPSF) * sg[c];       sbias0 = sb[c] - n0 * ss0;
    float n1 = sst[c + 1] * INV_M;
    float w1 = sst[128 + c + 1] * INV_M - n1 * n1;
    ss1 = rsqrtf(w1 + EPSF) * sg[c + 1];   sbias1 = sb[c + 1] - n1 * ss1;
  }
  const float lg0 = lg[c], lg1 = lg[c + 1], lb0 = lb[c], lb1 = lb[c + 1];
  const int wid = (blockIdx.x * 256 + threadIdx.x) >> 6;
  const int NW  = gridDim.x * 4;
  const int ROWS = FINAL ? NBATCH : MTOT;
  for (int r = wid; r < ROWS; r += NW) {
    const long m   = FINAL ? (long)r * SEQ : (long)r;
    const long off = m * DIM + c;
    float2 tv = *(const float2*)(t1 + off);
    float2 fv = *(const float2*)(ffr + off);
    uint sv = *(const uint*)(skr + off);
    float s0 = bf2f((ushort)(sv & 0xFFFFu)), s1 = bf2f((ushort)(sv >> 16));
    float y0 = tv.x + fv.x * fs0 + fbias0;
    float y1 = tv.y + fv.y * fs1 + fbias1;
    float s = y0 + y1, sq = y0 * y0 + y1 * y1;
#pragma unroll
    for (int o = 32; o; o >>= 1) { s += __shfl_xor(s, o); sq += __shfl_xor(sq, o); }
    const float mean = s * (1.f / 128.f);
    const float var  = sq * (1.f / 128.f) - mean * mean;
    const float rs   = rsqrtf(var + EPSF);
    float o0 = (y0 - mean) * rs * lg0 + lb0 + (s0 * ss0 + sbias0);
    float o1 = (y1 - mean) * rs * lg1 + lb1 + (s1 * ss1 + sbias1);
    const long ooff = FINAL ? ((long)r * DIM + c) : off;
    *(float2*)(out + ooff) = make_float2(o0, o1);
  }
}

// ---------------------------------------------------------------------------
extern "C" void kernel_launch(void* const* d_in, const int* in_sizes, int n_in,
                              void* d_out, int out_size, void* d_ws, size_t ws_size,
                              hipStream_t stream)
{
  (void)in_sizes; (void)n_in; (void)out_size; (void)ws_size;
  const float* x    = (const float*)d_in[0];
  const float* mask = (const float*)d_in[1];
  const float* linW = (const float*)d_in[2];
  const float* ing  = (const float*)d_in[4];
  const float* inb  = (const float*)d_in[5];
  const float* qW   = (const float*)d_in[6];
  const float* qg   = (const float*)d_in[8];
  const float* qb   = (const float*)d_in[9];
  const float* kW   = (const float*)d_in[10];
  const float* kg   = (const float*)d_in[12];
  const float* kb   = (const float*)d_in[13];
  const float* vW   = (const float*)d_in[14];
  const float* vg   = (const float*)d_in[16];
  const float* vb   = (const float*)d_in[17];
  const float* lng  = (const float*)d_in[18];
  const float* lnb  = (const float*)d_in[19];
  const float* ffW  = (const float*)d_in[20];
  const float* ffg  = (const float*)d_in[22];
  const float* ffb  = (const float*)d_in[23];
  const float* skW  = (const float*)d_in[24];
  const float* skg  = (const float*)d_in[26];
  const float* skb  = (const float*)d_in[27];

  const long MD = (long)MTOT * DIM;
  float*  stats = (float*)d_ws;                 // 11*256 floats
  float*  h     = (float*)d_ws + 4096;          // fp32 [M][128]; also out1/h_next
  ushort* qbuf  = (ushort*)(h + MD);            // bf16 head-major q
  ushort* kbuf  = qbuf + MD;                    // bf16 head-major k
  ushort* vbuf  = kbuf + MD;                    // bf16 head-major v
  ushort* sbuf  = vbuf + MD;                    // bf16 [M][128] skip_raw
  uint4*  mbits = (uint4*)(sbuf + MD);          // 2 MB; total ~194 MB
  float*  ffbuf = (float*)qbuf;                 // fp32 ff_raw over dead q+k (64MB)

  ushort* Wsw = (ushort*)d_out;                 // 352 KB of 512 KB; final
                                                // fuse2<true> overwrites all.
  hipMemsetAsync(stats, 0, 11 * 256 * sizeof(float), stream);

  WPtrs wp;
  wp.p[0] = linW;
  wp.p[1] = qW;            wp.p[2] = kW;            wp.p[3] = vW;
  wp.p[4] = ffW;           wp.p[5] = skW;
  wp.p[6] = qW + 16384;    wp.p[7] = kW + 16384;    wp.p[8] = vW + 16384;
  wp.p[9] = ffW + 16384;   wp.p[10] = skW + 16384;
  prep_w<<<88, 256, 0, stream>>>(wp, Wsw);
  pack_mask<<<512, 256, 0, stream>>>(mask, mbits);

  gemm_one<false, false><<<MTOT / 128, 256, 0, stream>>>(x, Wsw, h, stats);
  bn_apply<<<1024, 256, 0, stream>>>(h, stats, ing, inb);

  for (int l = 0; l < NLAYER; ++l) {
    const int poff = l * DIM;
    const ushort* wbase = Wsw + (1 + 5 * l) * 16384;
    float* stq = stats + (1 + 5 * l) * 256;
    float* stk = stats + (2 + 5 * l) * 256;
    float* stv = stats + (3 + 5 * l) * 256;
    float* stf = stats + (4 + 5 * l) * 256;
    float* sts = stats + (5 + 5 * l) * 256;

    gemm_qkvs<<<MTOT / 128, 256, 0, stream>>>(h, wbase, qbuf, kbuf, vbuf, sbuf,
                                              stq, stk, stv, sts);

    attn_ln<<<NBATCH, 256, 0, stream>>>(
        qbuf, kbuf, vbuf, h /* h in, out1 fp32 out (in-place) */, mbits,
        stq, stk, stv,
        qg + poff, qb + poff, kg + poff, kb + poff, vg + poff, vb + poff,
        lng + poff, lnb + poff);

    // ff_raw = gemm(out1); A fp32 from h region, out fp32 over dead q+k
    gemm_one<false, false><<<MTOT / 128, 256, 0, stream>>>(
        h, wbase + 3 * 16384, ffbuf, stf);

    if (l < NLAYER - 1) {
      fuse2_k<false><<<1024, 256, 0, stream>>>(
          h, ffbuf, sbuf, stf, sts,
          ffg + poff, ffb + poff, skg + poff, skb + poff,
          lng + poff, lnb + poff, h /* in-place */);
    } else {
      fuse2_k<true><<<64, 256, 0, stream>>>(
          h, ffbuf, sbuf, stf, sts,
          ffg + poff, ffb + poff, skg + poff, skb + poff,
          lng + poff, lnb + poff, (float*)d_out);
    }
  }
}

// Round 9
// 638.794 us; speedup vs baseline: 1.0502x; 1.0502x over previous
//
#include <hip/hip_runtime.h>
#include <hip/hip_bf16.h>

// ToyMDNN on MI355X — round 9: vectorize GEMM stores via per-wave LDS bounce.
//  * All GEMM outputs now leave through a per-wave 32x32 LDS transpose tile
//    and 16B/lane coalesced stores (r8: 2-4B scalar stores, 65K insts/block,
//    WRITE 168MB vs 128 ideal -> gemm_qkvs was store-issue bound at 1.4TB/s).
//  * skip (sbuf) and ff_raw (ffbuf) become HEAD-MAJOR so every GEMM uses the
//    same contiguous-tile store path; fuse2 reads them head-major. Values
//    bit-identical to r8 (same acc, same rounding points).
//  * everything else = r8 (fp32 out1 in-place in h, fused attn+LN, packed
//    mask, direct B-frag weights).
// N=1024 S=128 D=128 H=4 C=32 L=2. GEMM biases cancel through batch-norm.

typedef __attribute__((ext_vector_type(8))) short short8v;
typedef __attribute__((ext_vector_type(16))) float f32x16;

#define NBATCH 1024
#define SEQ    128
#define DIM    128
#define NLAYER 2
#define MTOT   (NBATCH*SEQ)
#define EPSF   1e-5f
#define INV_M  (1.0f/131072.0f)
#define HM32   ((long)MTOT * 32)     // head-major per-head region (elements)

__device__ __forceinline__ float bf2f(ushort s) {
  return __uint_as_float(((uint)s) << 16);
}
__device__ __forceinline__ ushort f2bf(float f) {
  uint u = __float_as_uint(f);
  return (ushort)((u + 0x7FFFu + ((u >> 16) & 1u)) >> 16);
}

struct WPtrs { const float* p[11]; };

// ---------------------------------------------------------------------------
// One-time: 11 weight matrices fp32 -> bf16 packed in B-fragment order:
// dst[m*16384 + kc*1024 + nt*256 + ln*8 + i] = W[nt*32+ln][kc*8+i].
// ---------------------------------------------------------------------------
__global__ __launch_bounds__(256) void prep_w(WPtrs wp, ushort* __restrict__ dst)
{
  const int gid = blockIdx.x * 256 + threadIdx.x;   // 88*256 = 11*2048
  const int m = gid >> 11;
  const int rem = gid & 2047;
  const int j = rem >> 4, kc = rem & 15;
  const float* src = wp.p[m];
  float4 a = *(const float4*)(src + j * DIM + kc * 8);
  float4 b = *(const float4*)(src + j * DIM + kc * 8 + 4);
  short8v v;
  v[0] = (short)f2bf(a.x); v[1] = (short)f2bf(a.y);
  v[2] = (short)f2bf(a.z); v[3] = (short)f2bf(a.w);
  v[4] = (short)f2bf(b.x); v[5] = (short)f2bf(b.y);
  v[6] = (short)f2bf(b.z); v[7] = (short)f2bf(b.w);
  const int nt = j >> 5, ln = j & 31;
  *(short8v*)(dst + m * 16384 + kc * 1024 + nt * 256 + ln * 8) = v;
}

// ---------------------------------------------------------------------------
// One-time: pack 0/1 fp32 mask rows into 128-bit rows (uint4).
// ---------------------------------------------------------------------------
__global__ __launch_bounds__(256) void pack_mask(
    const float* __restrict__ mask, uint4* __restrict__ mb)
{
  const int lane = threadIdx.x & 63;
  const int wv   = (blockIdx.x * 256 + threadIdx.x) >> 6;
  const int NW   = gridDim.x * 4;
  for (int row = wv; row < MTOT; row += NW) {
    const float a = mask[(long)row * SEQ + lane];
    const float b = mask[(long)row * SEQ + 64 + lane];
    const unsigned long long lo = __ballot(a != 0.f);
    const unsigned long long hi = __ballot(b != 0.f);
    if (lane == 0) {
      uint4 w;
      w.x = (uint)lo; w.y = (uint)(lo >> 32);
      w.z = (uint)hi; w.w = (uint)(hi >> 32);
      mb[row] = w;
    }
  }
}

// ---------------------------------------------------------------------------
// Single GEMM: out[m][j] = sum_k A[m][k]*W[j][k] + column stats.
// A fp32 [M][128]. OM=0: out fp32 [M][128]; OM=1: out fp32 head-major.
// Stores leave via per-wave LDS transpose tile (16B/lane coalesced).
// ---------------------------------------------------------------------------
template<int OM>
__global__ __launch_bounds__(256, 3) void gemm_one(
    const float* __restrict__ A, const ushort* __restrict__ Wm,
    float* __restrict__ outp, float* __restrict__ stats)
{
  __shared__ float tb[4][32 * 32];   // per-wave transpose tile (16 KB)
  __shared__ float csum[128], csq[128];
  const int tid = threadIdx.x;
  const int lane = tid & 63, wid = tid >> 6;
  const int hi = lane >> 5, ln = lane & 31;
  const long m0 = (long)blockIdx.x * 128;
  const long arow = m0 + wid * 32 + ln;

  if (tid < 128) { csum[tid] = 0.f; csq[tid] = 0.f; }

  short8v afr[8];
  {
    const float* ar = A + arow * DIM + hi * 8;
#pragma unroll
    for (int kt = 0; kt < 8; ++kt) {
      float4 a0 = *(const float4*)(ar + kt * 16);
      float4 a1 = *(const float4*)(ar + kt * 16 + 4);
      short8v v;
      v[0] = (short)f2bf(a0.x); v[1] = (short)f2bf(a0.y);
      v[2] = (short)f2bf(a0.z); v[3] = (short)f2bf(a0.w);
      v[4] = (short)f2bf(a1.x); v[5] = (short)f2bf(a1.y);
      v[6] = (short)f2bf(a1.z); v[7] = (short)f2bf(a1.w);
      afr[kt] = v;
    }
  }

  f32x16 acc[4];
#pragma unroll
  for (int nt = 0; nt < 4; ++nt)
#pragma unroll
    for (int r = 0; r < 16; ++r) acc[nt][r] = 0.f;

#pragma unroll
  for (int kt = 0; kt < 8; ++kt) {
    const ushort* wb = Wm + (kt * 2 + hi) * 1024 + ln * 8;
#pragma unroll
    for (int nt = 0; nt < 4; ++nt) {
      short8v b = *(const short8v*)(wb + nt * 256);
      acc[nt] = __builtin_amdgcn_mfma_f32_32x32x16_bf16(afr[kt], b, acc[nt], 0, 0, 0);
    }
  }

  float ps[4], pq[4];
#pragma unroll
  for (int nt = 0; nt < 4; ++nt) { ps[nt] = 0.f; pq[nt] = 0.f; }

#pragma unroll
  for (int nt = 0; nt < 4; ++nt) {
    // dump 32x32 tile into per-wave LDS (lane=col, regs=rows)
#pragma unroll
    for (int r = 0; r < 16; ++r) {
      const float v = acc[nt][r];
      ps[nt] += v; pq[nt] += v * v;
      const int row = (r & 3) + 8 * (r >> 2) + 4 * hi;
      tb[wid][row * 32 + ln] = v;
    }
    // coalesced 16B/lane stores
    if constexpr (OM == 0) {
#pragma unroll
      for (int i = 0; i < 4; ++i) {
        const int row = i * 8 + (lane >> 3);
        float4 v = *(const float4*)&tb[wid][row * 32 + (lane & 7) * 4];
        *(float4*)(outp + (m0 + wid * 32 + row) * DIM + nt * 32 + (lane & 7) * 4) = v;
      }
    } else {
      float* dst = outp + (long)nt * HM32 + (m0 + wid * 32) * 32;
#pragma unroll
      for (int i = 0; i < 4; ++i) {
        float4 v = *(const float4*)&tb[wid][i * 256 + lane * 4];
        *(float4*)(dst + i * 256 + lane * 4) = v;
      }
    }
  }

#pragma unroll
  for (int nt = 0; nt < 4; ++nt) {
    ps[nt] += __shfl_xor(ps[nt], 32);
    pq[nt] += __shfl_xor(pq[nt], 32);
  }
  __syncthreads();
  if (hi == 0) {
#pragma unroll
    for (int nt = 0; nt < 4; ++nt) {
      atomicAdd(&csum[nt * 32 + ln], ps[nt]);
      atomicAdd(&csq[nt * 32 + ln], pq[nt]);
    }
  }
  __syncthreads();
  if (tid < 128) {
    atomicAdd(&stats[tid],       csum[tid]);
    atomicAdd(&stats[128 + tid], csq[tid]);
  }
}

// ---------------------------------------------------------------------------
// Fused Q/K/V/SKIP GEMM. A (fp32 h) read once; 4 weight matrices (offsets
// 0,1,2,4 from wbase) as direct B-frags. ALL outputs head-major bf16,
// stored via per-wave LDS bounce (2KB contiguous tile per (w,nt,wave)).
// ---------------------------------------------------------------------------
__global__ __launch_bounds__(256, 2) void gemm_qkvs(
    const float* __restrict__ A, const ushort* __restrict__ wbase,
    ushort* __restrict__ o0, ushort* __restrict__ o1,
    ushort* __restrict__ o2, ushort* __restrict__ o3,
    float* __restrict__ st0, float* __restrict__ st1,
    float* __restrict__ st2, float* __restrict__ st3)
{
  __shared__ ushort qtb[4][32 * 32];   // per-wave transpose tile (8 KB)
  __shared__ float csum[128], csq[128];
  const int tid = threadIdx.x;
  const int lane = tid & 63, wid = tid >> 6;
  const int hi = lane >> 5, ln = lane & 31;
  const long m0 = (long)blockIdx.x * 128;
  const long arow = m0 + wid * 32 + ln;

  if (tid < 128) { csum[tid] = 0.f; csq[tid] = 0.f; }

  short8v afr[8];
  {
    const float* ar = A + arow * DIM + hi * 8;
#pragma unroll
    for (int kt = 0; kt < 8; ++kt) {
      float4 a0 = *(const float4*)(ar + kt * 16);
      float4 a1 = *(const float4*)(ar + kt * 16 + 4);
      short8v v;
      v[0] = (short)f2bf(a0.x); v[1] = (short)f2bf(a0.y);
      v[2] = (short)f2bf(a0.z); v[3] = (short)f2bf(a0.w);
      v[4] = (short)f2bf(a1.x); v[5] = (short)f2bf(a1.y);
      v[6] = (short)f2bf(a1.z); v[7] = (short)f2bf(a1.w);
      afr[kt] = v;
    }
  }

  float ps[4][4], pq[4][4];
#pragma unroll
  for (int w = 0; w < 4; ++w)
#pragma unroll
    for (int nt = 0; nt < 4; ++nt) { ps[w][nt] = 0.f; pq[w][nt] = 0.f; }

#pragma unroll
  for (int w = 0; w < 4; ++w) {
    const ushort* Wm = wbase + ((w < 3) ? w : 4) * 16384;

    f32x16 acc[4];
#pragma unroll
    for (int nt = 0; nt < 4; ++nt)
#pragma unroll
      for (int r = 0; r < 16; ++r) acc[nt][r] = 0.f;
#pragma unroll
    for (int kt = 0; kt < 8; ++kt) {
      const ushort* wb = Wm + (kt * 2 + hi) * 1024 + ln * 8;
#pragma unroll
      for (int nt = 0; nt < 4; ++nt) {
        short8v b = *(const short8v*)(wb + nt * 256);
        acc[nt] = __builtin_amdgcn_mfma_f32_32x32x16_bf16(afr[kt], b, acc[nt], 0, 0, 0);
      }
    }

    ushort* outp = (w == 0) ? o0 : (w == 1) ? o1 : (w == 2) ? o2 : o3;
#pragma unroll
    for (int nt = 0; nt < 4; ++nt) {
#pragma unroll
      for (int r = 0; r < 16; ++r) {
        const float v = acc[nt][r];
        ps[w][nt] += v; pq[w][nt] += v * v;
        const int row = (r & 3) + 8 * (r >> 2) + 4 * hi;
        qtb[wid][row * 32 + ln] = f2bf(v);
      }
      ushort* dst = outp + (long)nt * HM32 + (m0 + wid * 32) * 32;
      short8v v0 = *(const short8v*)&qtb[wid][lane * 8];
      short8v v1 = *(const short8v*)&qtb[wid][512 + lane * 8];
      *(short8v*)(dst + lane * 8)       = v0;
      *(short8v*)(dst + 512 + lane * 8) = v1;
    }
  }

  __syncthreads();
#pragma unroll
  for (int w = 0; w < 4; ++w) {
    float* st = (w == 0) ? st0 : (w == 1) ? st1 : (w == 2) ? st2 : st3;
    float lps[4], lpq[4];
#pragma unroll
    for (int nt = 0; nt < 4; ++nt) {
      lps[nt] = ps[w][nt] + __shfl_xor(ps[w][nt], 32);
      lpq[nt] = pq[w][nt] + __shfl_xor(pq[w][nt], 32);
    }
    if (hi == 0) {
#pragma unroll
      for (int nt = 0; nt < 4; ++nt) {
        atomicAdd(&csum[nt * 32 + ln], lps[nt]);
        atomicAdd(&csq[nt * 32 + ln],  lpq[nt]);
      }
    }
    __syncthreads();
    if (tid < 128) {
      atomicAdd(&st[tid],       csum[tid]);
      atomicAdd(&st[128 + tid], csq[tid]);
      csum[tid] = 0.f; csq[tid] = 0.f;
    }
    __syncthreads();
  }
}

// ---------------------------------------------------------------------------
// In-place BN apply for h (fp32).
// ---------------------------------------------------------------------------
__global__ __launch_bounds__(256) void bn_apply(
    float* __restrict__ x, const float* __restrict__ st,
    const float* __restrict__ g, const float* __restrict__ b)
{
  __shared__ float sc[128], bi[128];
  const int tid = threadIdx.x;
  if (tid < 128) {
    float mean = st[tid] * INV_M;
    float var  = st[128 + tid] * INV_M - mean * mean;
    float s = rsqrtf(var + EPSF) * g[tid];
    sc[tid] = s;
    bi[tid] = b[tid] - mean * s;
  }
  __syncthreads();
  const long total4 = (long)MTOT * DIM / 4;
  for (long i = (long)blockIdx.x * 256 + tid; i < total4; i += (long)gridDim.x * 256) {
    float4 vv = ((const float4*)x)[i];
    const int c = (int)((i * 4) & 127);
    vv.x = vv.x * sc[c + 0] + bi[c + 0];
    vv.y = vv.y * sc[c + 1] + bi[c + 1];
    vv.z = vv.z * sc[c + 2] + bi[c + 2];
    vv.w = vv.w * sc[c + 3] + bi[c + 3];
    ((float4*)x)[i] = vv;
  }
}

// ---------------------------------------------------------------------------
// Attention + fused LN(agg+h). One block per n; wave = head.
// S^T = mfma(K,Q) -> in-lane softmax; PV from D-regs; V BN folded via
// sum(P)=1; y = vs*o+vb0 + h (fp32); LN across waves via LDS reduce;
// out1 written FP32 IN-PLACE over h ([M][128]).
// ---------------------------------------------------------------------------
__global__ __launch_bounds__(256, 4) void attn_ln(
    const ushort* __restrict__ q, const ushort* __restrict__ k_in,
    const ushort* __restrict__ v_in,
    float* hbuf,                      // h in, out1 out (aliased on purpose)
    const uint4* __restrict__ mb,
    const float* __restrict__ qst, const float* __restrict__ kst, const float* __restrict__ vst,
    const float* __restrict__ qg, const float* __restrict__ qbb,
    const float* __restrict__ kg, const float* __restrict__ kbb,
    const float* __restrict__ vg, const float* __restrict__ vbb,
    const float* __restrict__ lng, const float* __restrict__ lnb)
{
  __shared__ ushort Vp[128 * 136];          // [c_global][slot(t)]
  __shared__ float qsc[128], qbi[128], ksc[128], kbi[128];
  __shared__ float reds[32][4], redq[32][4];
  __shared__ float2 rmv[32];

  const int tid = threadIdx.x;
  const int lane = tid & 63, hh = tid >> 6;
  const int hi = lane >> 5, ln = lane & 31;
  const int n = blockIdx.x;
  const long nb = (long)n * SEQ;            // global row base
  const long hbase = (long)hh * HM32 + nb * 32;

  if (tid < 128) {
    const int c = tid;
    float m, v, s;
    m = qst[c] * INV_M; v = qst[128 + c] * INV_M - m * m;
    s = rsqrtf(v + EPSF) * qg[c];  qsc[c] = s; qbi[c] = qbb[c] - m * s;
    m = kst[c] * INV_M; v = kst[128 + c] * INV_M - m * m;
    s = rsqrtf(v + EPSF) * kg[c];  ksc[c] = s; kbi[c] = kbb[c] - m * s;
  }
  const int cg = hh * 32 + ln;              // global output column
  float vs, vb0;
  {
    float m = vst[cg] * INV_M;
    float v = vst[128 + cg] * INV_M - m * m;
    vs = rsqrtf(v + EPSF) * vg[cg];
    vb0 = vbb[cg] - m * vs;
  }
  const float lgc = lng[cg], lbc = lnb[cg];

  // stage own head's V slice (dense 8KB) into permuted slots
#pragma unroll
  for (int it = 0; it < 8; ++it) {
    const int t = it * 16 + (lane >> 2);
    const int c0 = (lane & 3) * 8;
    short8v vv = *(const short8v*)(v_in + hbase + (long)t * 32 + c0);
    const int tl = t & 31;
    const int kt = tl >> 4;
    const int rem = tl & 15;
    const int slot = (t & 96) + (kt << 4) + ((rem >> 2) & 1) * 8 + ((rem & 3) | (((rem >> 3) & 1) << 2));
#pragma unroll
    for (int i = 0; i < 8; ++i) Vp[(hh * 32 + c0 + i) * 136 + slot] = (ushort)vv[i];
  }
  __syncthreads();

  // normalized K fragments, cached for all row-tiles
  short8v kfr[4][2];
#pragma unroll
  for (int nt = 0; nt < 4; ++nt)
#pragma unroll
    for (int kt = 0; kt < 2; ++kt) {
      short8v raw = *(const short8v*)(k_in + hbase + (long)(nt * 32 + ln) * 32 + kt * 16 + hi * 8);
      short8v f;
#pragma unroll
      for (int i = 0; i < 8; ++i) {
        const int c = hh * 32 + kt * 16 + hi * 8 + i;
        f[i] = (short)f2bf(bf2f((ushort)raw[i]) * ksc[c] + kbi[c]);
      }
      kfr[nt][kt] = f;
    }

  for (int mt = 0; mt < 4; ++mt) {
    // normalized Q fragments (B operand): col s = mt*32+ln
    short8v qfr[2];
#pragma unroll
    for (int kt = 0; kt < 2; ++kt) {
      short8v raw = *(const short8v*)(q + hbase + (long)(mt * 32 + ln) * 32 + kt * 16 + hi * 8);
      short8v f;
#pragma unroll
      for (int i = 0; i < 8; ++i) {
        const int c = hh * 32 + kt * 16 + hi * 8 + i;
        f[i] = (short)f2bf(bf2f((ushort)raw[i]) * qsc[c] + qbi[c]);
      }
      qfr[kt] = f;
    }

    f32x16 st[4];
#pragma unroll
    for (int nt = 0; nt < 4; ++nt)
#pragma unroll
      for (int r = 0; r < 16; ++r) st[nt][r] = 0.f;
#pragma unroll
    for (int nt = 0; nt < 4; ++nt) {
      st[nt] = __builtin_amdgcn_mfma_f32_32x32x16_bf16(kfr[nt][0], qfr[0], st[nt], 0, 0, 0);
      st[nt] = __builtin_amdgcn_mfma_f32_32x32x16_bf16(kfr[nt][1], qfr[1], st[nt], 0, 0, 0);
    }

    // mask + in-lane softmax (softmax(alpha*mask) semantics)
    const uint4 bw = mb[nb + mt * 32 + ln];
    float mx = -1e30f;
#pragma unroll
    for (int nt = 0; nt < 4; ++nt) {
      const uint word = (nt == 0) ? bw.x : (nt == 1) ? bw.y : (nt == 2) ? bw.z : bw.w;
#pragma unroll
      for (int r = 0; r < 16; ++r) {
        const int crow = (r & 3) + 8 * (r >> 2) + 4 * hi;
        st[nt][r] = ((word >> crow) & 1u) ? st[nt][r] : 0.f;
        mx = fmaxf(mx, st[nt][r]);
      }
    }
    mx = fmaxf(mx, __shfl_xor(mx, 32));
    float sum = 0.f;
#pragma unroll
    for (int nt = 0; nt < 4; ++nt)
#pragma unroll
      for (int r = 0; r < 16; ++r) {
        const float e = __expf(st[nt][r] - mx);
        st[nt][r] = e;
        sum += e;
      }
    sum += __shfl_xor(sum, 32);
    const float inv = 1.f / sum;

    // O = P · V_raw
    f32x16 o;
#pragma unroll
    for (int r = 0; r < 16; ++r) o[r] = 0.f;
#pragma unroll
    for (int nt = 0; nt < 4; ++nt) {
#pragma unroll
      for (int kt = 0; kt < 2; ++kt) {
        short8v pa;
#pragma unroll
        for (int j = 0; j < 8; ++j) pa[j] = (short)f2bf(st[nt][kt * 8 + j] * inv);
        short8v vb = *(const short8v*)&Vp[(long)cg * 136 + nt * 32 + kt * 16 + hi * 8];
        o = __builtin_amdgcn_mfma_f32_32x32x16_bf16(pa, vb, o, 0, 0, 0);
      }
    }

    // y = BN_v-folded agg + h  (fp32)
    float yv[16];
#pragma unroll
    for (int r = 0; r < 16; ++r) {
      const int sl = (r & 3) + 8 * (r >> 2) + 4 * hi;
      const float hval = hbuf[(nb + mt * 32 + sl) * DIM + cg];
      yv[r] = vs * o[r] + vb0 + hval;
    }

    // LN across full row: intra-half butterfly + cross-wave LDS reduce
#pragma unroll
    for (int r = 0; r < 16; ++r) {
      float s = yv[r], q2 = yv[r] * yv[r];
      s += __shfl_xor(s, 1);  q2 += __shfl_xor(q2, 1);
      s += __shfl_xor(s, 2);  q2 += __shfl_xor(q2, 2);
      s += __shfl_xor(s, 4);  q2 += __shfl_xor(q2, 4);
      s += __shfl_xor(s, 8);  q2 += __shfl_xor(q2, 8);
      s += __shfl_xor(s, 16); q2 += __shfl_xor(q2, 16);
      if (ln == 0) {
        const int sl = (r & 3) + 8 * (r >> 2) + 4 * hi;
        reds[sl][hh] = s; redq[sl][hh] = q2;
      }
    }
    __syncthreads();
    if (tid < 32) {
      const float s  = reds[tid][0] + reds[tid][1] + reds[tid][2] + reds[tid][3];
      const float q2 = redq[tid][0] + redq[tid][1] + redq[tid][2] + redq[tid][3];
      const float mean = s * (1.f / 128.f);
      const float var  = q2 * (1.f / 128.f) - mean * mean;
      rmv[tid] = make_float2(mean, rsqrtf(var + EPSF));
    }
    __syncthreads();
    // out1 fp32 in-place over h
#pragma unroll
    for (int r = 0; r < 16; ++r) {
      const int sl = (r & 3) + 8 * (r >> 2) + 4 * hi;
      const float2 mr = rmv[sl];
      hbuf[(nb + mt * 32 + sl) * DIM + cg] = (yv[r] - mr.x) * mr.y * lgc + lbc;
    }
  }
}

// ---------------------------------------------------------------------------
// h_new = LN(out1 + BN_ff(ff_raw)) + BN_skip(skip_raw).
// t1 (out1) fp32 [M][128]; ffr fp32 HEAD-MAJOR; skr bf16 HEAD-MAJOR.
// Non-final: out == t1 (in-place). FINAL: rows m=n*S -> d_out (N,128).
// ---------------------------------------------------------------------------
template <bool FINAL>
__global__ __launch_bounds__(256) void fuse2_k(
    const float* t1, const float* __restrict__ ffr, const ushort* __restrict__ skr,
    const float* __restrict__ fst, const float* __restrict__ sst,
    const float* __restrict__ fg, const float* __restrict__ fb,
    const float* __restrict__ sg, const float* __restrict__ sb,
    const float* __restrict__ lg, const float* __restrict__ lb,
    float* out)
{
  const int lane = threadIdx.x & 63;
  const int c = lane * 2;
  float fs0, fbias0, fs1, fbias1, ss0, sbias0, ss1, sbias1;
  {
    float m0 = fst[c] * INV_M;
    float v0 = fst[128 + c] * INV_M - m0 * m0;
    fs0 = rsqrtf(v0 + EPSF) * fg[c];       fbias0 = fb[c] - m0 * fs0;
    float m1 = fst[c + 1] * INV_M;
    float v1 = fst[128 + c + 1] * INV_M - m1 * m1;
    fs1 = rsqrtf(v1 + EPSF) * fg[c + 1];   fbias1 = fb[c + 1] - m1 * fs1;
    float n0 = sst[c] * INV_M;
    float w0 = sst[128 + c] * INV_M - n0 * n0;
    ss0 = rsqrtf(w0 + EPSF) * sg[c];       sbias0 = sb[c] - n0 * ss0;
    float n1 = sst[c + 1] * INV_M;
    float w1 = sst[128 + c + 1] * INV_M - n1 * n1;
    ss1 = rsqrtf(w1 + EPSF) * sg[c + 1];   sbias1 = sb[c + 1] - n1 * ss1;
  }
  const float lg0 = lg[c], lg1 = lg[c + 1], lb0 = lb[c], lb1 = lb[c + 1];
  const int wid = (blockIdx.x * 256 + threadIdx.x) >> 6;
  const int NW  = gridDim.x * 4;
  const int ROWS = FINAL ? NBATCH : MTOT;
  const long thm = (long)(c >> 5) * HM32;       // head region of cols c, c+1
  for (int r = wid; r < ROWS; r += NW) {
    const long m   = FINAL ? (long)r * SEQ : (long)r;
    const long off = m * DIM + c;
    const long hm  = thm + m * 32 + (c & 31);
    float2 tv = *(const float2*)(t1 + off);
    float2 fv = *(const float2*)(ffr + hm);
    uint sv = *(const uint*)(skr + hm);
    float s0 = bf2f((ushort)(sv & 0xFFFFu)), s1 = bf2f((ushort)(sv >> 16));
    float y0 = tv.x + fv.x * fs0 + fbias0;
    float y1 = tv.y + fv.y * fs1 + fbias1;
    float s = y0 + y1, sq = y0 * y0 + y1 * y1;
#pragma unroll
    for (int o = 32; o; o >>= 1) { s += __shfl_xor(s, o); sq += __shfl_xor(sq, o); }
    const float mean = s * (1.f / 128.f);
    const float var  = sq * (1.f / 128.f) - mean * mean;
    const float rs   = rsqrtf(var + EPSF);
    float o0 = (y0 - mean) * rs * lg0 + lb0 + (s0 * ss0 + sbias0);
    float o1 = (y1 - mean) * rs * lg1 + lb1 + (s1 * ss1 + sbias1);
    const long ooff = FINAL ? ((long)r * DIM + c) : off;
    *(float2*)(out + ooff) = make_float2(o0, o1);
  }
}

// ---------------------------------------------------------------------------
extern "C" void kernel_launch(void* const* d_in, const int* in_sizes, int n_in,
                              void* d_out, int out_size, void* d_ws, size_t ws_size,
                              hipStream_t stream)
{
  (void)in_sizes; (void)n_in; (void)out_size; (void)ws_size;
  const float* x    = (const float*)d_in[0];
  const float* mask = (const float*)d_in[1];
  const float* linW = (const float*)d_in[2];
  const float* ing  = (const float*)d_in[4];
  const float* inb  = (const float*)d_in[5];
  const float* qW   = (const float*)d_in[6];
  const float* qg   = (const float*)d_in[8];
  const float* qb   = (const float*)d_in[9];
  const float* kW   = (const float*)d_in[10];
  const float* kg   = (const float*)d_in[12];
  const float* kb   = (const float*)d_in[13];
  const float* vW   = (const float*)d_in[14];
  const float* vg   = (const float*)d_in[16];
  const float* vb   = (const float*)d_in[17];
  const float* lng  = (const float*)d_in[18];
  const float* lnb  = (const float*)d_in[19];
  const float* ffW  = (const float*)d_in[20];
  const float* ffg  = (const float*)d_in[22];
  const float* ffb  = (const float*)d_in[23];
  const float* skW  = (const float*)d_in[24];
  const float* skg  = (const float*)d_in[26];
  const float* skb  = (const float*)d_in[27];

  const long MD = (long)MTOT * DIM;
  float*  stats = (float*)d_ws;                 // 11*256 floats
  float*  h     = (float*)d_ws + 4096;          // fp32 [M][128]; also out1/h_next
  ushort* qbuf  = (ushort*)(h + MD);            // bf16 head-major q
  ushort* kbuf  = qbuf + MD;                    // bf16 head-major k
  ushort* vbuf  = kbuf + MD;                    // bf16 head-major v
  ushort* sbuf  = vbuf + MD;                    // bf16 head-major skip_raw
  uint4*  mbits = (uint4*)(sbuf + MD);          // 2 MB; total ~194 MB
  float*  ffbuf = (float*)qbuf;                 // fp32 head-major ff over dead q+k

  ushort* Wsw = (ushort*)d_out;                 // 352 KB of 512 KB; final
                                                // fuse2<true> overwrites all.
  hipMemsetAsync(stats, 0, 11 * 256 * sizeof(float), stream);

  WPtrs wp;
  wp.p[0] = linW;
  wp.p[1] = qW;            wp.p[2] = kW;            wp.p[3] = vW;
  wp.p[4] = ffW;           wp.p[5] = skW;
  wp.p[6] = qW + 16384;    wp.p[7] = kW + 16384;    wp.p[8] = vW + 16384;
  wp.p[9] = ffW + 16384;   wp.p[10] = skW + 16384;
  prep_w<<<88, 256, 0, stream>>>(wp, Wsw);
  pack_mask<<<512, 256, 0, stream>>>(mask, mbits);

  gemm_one<0><<<MTOT / 128, 256, 0, stream>>>(x, Wsw, h, stats);
  bn_apply<<<1024, 256, 0, stream>>>(h, stats, ing, inb);

  for (int l = 0; l < NLAYER; ++l) {
    const int poff = l * DIM;
    const ushort* wbase = Wsw + (1 + 5 * l) * 16384;
    float* stq = stats + (1 + 5 * l) * 256;
    float* stk = stats + (2 + 5 * l) * 256;
    float* stv = stats + (3 + 5 * l) * 256;
    float* stf = stats + (4 + 5 * l) * 256;
    float* sts = stats + (5 + 5 * l) * 256;

    gemm_qkvs<<<MTOT / 128, 256, 0, stream>>>(h, wbase, qbuf, kbuf, vbuf, sbuf,
                                              stq, stk, stv, sts);

    attn_ln<<<NBATCH, 256, 0, stream>>>(
        qbuf, kbuf, vbuf, h /* h in, out1 fp32 out (in-place) */, mbits,
        stq, stk, stv,
        qg + poff, qb + poff, kg + poff, kb + poff, vg + poff, vb + poff,
        lng + poff, lnb + poff);

    // ff_raw = gemm(out1); A fp32 row-major from h, out fp32 HEAD-MAJOR
    gemm_one<1><<<MTOT / 128, 256, 0, stream>>>(
        h, wbase + 3 * 16384, ffbuf, stf);

    if (l < NLAYER - 1) {
      fuse2_k<false><<<1024, 256, 0, stream>>>(
          h, ffbuf, sbuf, stf, sts,
          ffg + poff, ffb + poff, skg + poff, skb + poff,
          lng + poff, lnb + poff, h /* in-place */);
    } else {
      fuse2_k<true><<<64, 256, 0, stream>>>(
          h, ffbuf, sbuf, stf, sts,
          ffg + poff, ffb + poff, skg + poff, skb + poff,
          lng + poff, lnb + poff, (float*)d_out);
    }
  }
}

// Round 10
// 513.973 us; speedup vs baseline: 1.3053x; 1.2429x over previous
//
#include <hip/hip_runtime.h>
#include <hip/hip_bf16.h>

// ToyMDNN on MI355X — round 10: weights via LDS (conflict-free packed layout,
// double-buffered in qkvs) instead of per-MFMA direct-global B-frags.
//  * r9 counters: gemm_qkvs MfmaUtil 4.6%, VALUBusy 6.6%, 1.24 TB/s ->
//    latency-bound on L2 B-frag loads (VGPR=128 caps prefetch depth).
//  * qkvs: stage 32KB/w in LDS dbuf; next-w global loads issued BEFORE the
//    current-w MFMA block (256cy of MFMA covers L2 latency); 1 barrier/w.
//    LDS reads linear ln*16 within 1KB chunks -> conflict-free.
//  * gemm_one: single 32KB W staged once; 3 blocks/CU.
//  * stats epilogue in qkvs: per-w csum arrays (8 barriers -> 2).
//  * values bit-identical to r9 (absmax 0.1445 expected unchanged).
// N=1024 S=128 D=128 H=4 C=32 L=2. GEMM biases cancel through batch-norm.

typedef __attribute__((ext_vector_type(8))) short short8v;
typedef __attribute__((ext_vector_type(16))) float f32x16;

#define NBATCH 1024
#define SEQ    128
#define DIM    128
#define NLAYER 2
#define MTOT   (NBATCH*SEQ)
#define EPSF   1e-5f
#define INV_M  (1.0f/131072.0f)
#define HM32   ((long)MTOT * 32)     // head-major per-head region (elements)

__device__ __forceinline__ float bf2f(ushort s) {
  return __uint_as_float(((uint)s) << 16);
}
__device__ __forceinline__ ushort f2bf(float f) {
  uint u = __float_as_uint(f);
  return (ushort)((u + 0x7FFFu + ((u >> 16) & 1u)) >> 16);
}

struct WPtrs { const float* p[11]; };

// ---------------------------------------------------------------------------
// One-time: 11 weight matrices fp32 -> bf16 packed in B-fragment order:
// dst[m*16384 + kc*1024 + nt*256 + ln*8 + i] = W[nt*32+ln][kc*8+i].
// ---------------------------------------------------------------------------
__global__ __launch_bounds__(256) void prep_w(WPtrs wp, ushort* __restrict__ dst)
{
  const int gid = blockIdx.x * 256 + threadIdx.x;   // 88*256 = 11*2048
  const int m = gid >> 11;
  const int rem = gid & 2047;
  const int j = rem >> 4, kc = rem & 15;
  const float* src = wp.p[m];
  float4 a = *(const float4*)(src + j * DIM + kc * 8);
  float4 b = *(const float4*)(src + j * DIM + kc * 8 + 4);
  short8v v;
  v[0] = (short)f2bf(a.x); v[1] = (short)f2bf(a.y);
  v[2] = (short)f2bf(a.z); v[3] = (short)f2bf(a.w);
  v[4] = (short)f2bf(b.x); v[5] = (short)f2bf(b.y);
  v[6] = (short)f2bf(b.z); v[7] = (short)f2bf(b.w);
  const int nt = j >> 5, ln = j & 31;
  *(short8v*)(dst + m * 16384 + kc * 1024 + nt * 256 + ln * 8) = v;
}

// ---------------------------------------------------------------------------
// One-time: pack 0/1 fp32 mask rows into 128-bit rows (uint4).
// ---------------------------------------------------------------------------
__global__ __launch_bounds__(256) void pack_mask(
    const float* __restrict__ mask, uint4* __restrict__ mb)
{
  const int lane = threadIdx.x & 63;
  const int wv   = (blockIdx.x * 256 + threadIdx.x) >> 6;
  const int NW   = gridDim.x * 4;
  for (int row = wv; row < MTOT; row += NW) {
    const float a = mask[(long)row * SEQ + lane];
    const float b = mask[(long)row * SEQ + 64 + lane];
    const unsigned long long lo = __ballot(a != 0.f);
    const unsigned long long hi = __ballot(b != 0.f);
    if (lane == 0) {
      uint4 w;
      w.x = (uint)lo; w.y = (uint)(lo >> 32);
      w.z = (uint)hi; w.w = (uint)(hi >> 32);
      mb[row] = w;
    }
  }
}

// ---------------------------------------------------------------------------
// Single GEMM: out[m][j] = sum_k A[m][k]*W[j][k] + column stats.
// W staged once into LDS (packed layout, conflict-free reads).
// OM=0: out fp32 [M][128]; OM=1: out fp32 head-major.
// ---------------------------------------------------------------------------
template<int OM>
__global__ __launch_bounds__(256, 3) void gemm_one(
    const float* __restrict__ A, const ushort* __restrict__ Wm,
    float* __restrict__ outp, float* __restrict__ stats)
{
  __shared__ ushort Wl[16384];       // 32 KB staged weights
  __shared__ float tb[4][1024];      // per-wave transpose tile (16 KB)
  __shared__ float csum[128], csq[128];
  const int tid = threadIdx.x;
  const int lane = tid & 63, wid = tid >> 6;
  const int hi = lane >> 5, ln = lane & 31;
  const long m0 = (long)blockIdx.x * 128;
  const long arow = m0 + wid * 32 + ln;

  // stage W (coalesced 16B copy)
#pragma unroll
  for (int i = 0; i < 8; ++i)
    ((short8v*)Wl)[i * 256 + tid] = ((const short8v*)Wm)[i * 256 + tid];

  if (tid < 128) { csum[tid] = 0.f; csq[tid] = 0.f; }

  short8v afr[8];
  {
    const float* ar = A + arow * DIM + hi * 8;
#pragma unroll
    for (int kt = 0; kt < 8; ++kt) {
      float4 a0 = *(const float4*)(ar + kt * 16);
      float4 a1 = *(const float4*)(ar + kt * 16 + 4);
      short8v v;
      v[0] = (short)f2bf(a0.x); v[1] = (short)f2bf(a0.y);
      v[2] = (short)f2bf(a0.z); v[3] = (short)f2bf(a0.w);
      v[4] = (short)f2bf(a1.x); v[5] = (short)f2bf(a1.y);
      v[6] = (short)f2bf(a1.z); v[7] = (short)f2bf(a1.w);
      afr[kt] = v;
    }
  }
  __syncthreads();

  f32x16 acc[4];
#pragma unroll
  for (int nt = 0; nt < 4; ++nt)
#pragma unroll
    for (int r = 0; r < 16; ++r) acc[nt][r] = 0.f;

#pragma unroll
  for (int kt = 0; kt < 8; ++kt) {
    const ushort* wb = Wl + (kt * 2 + hi) * 1024 + ln * 8;
#pragma unroll
    for (int nt = 0; nt < 4; ++nt) {
      short8v b = *(const short8v*)(wb + nt * 256);
      acc[nt] = __builtin_amdgcn_mfma_f32_32x32x16_bf16(afr[kt], b, acc[nt], 0, 0, 0);
    }
  }

  float ps[4], pq[4];
#pragma unroll
  for (int nt = 0; nt < 4; ++nt) { ps[nt] = 0.f; pq[nt] = 0.f; }

#pragma unroll
  for (int nt = 0; nt < 4; ++nt) {
#pragma unroll
    for (int r = 0; r < 16; ++r) {
      const float v = acc[nt][r];
      ps[nt] += v; pq[nt] += v * v;
      const int row = (r & 3) + 8 * (r >> 2) + 4 * hi;
      tb[wid][row * 32 + ln] = v;
    }
    if constexpr (OM == 0) {
#pragma unroll
      for (int i = 0; i < 4; ++i) {
        const int row = i * 8 + (lane >> 3);
        float4 v = *(const float4*)&tb[wid][row * 32 + (lane & 7) * 4];
        *(float4*)(outp + (m0 + wid * 32 + row) * DIM + nt * 32 + (lane & 7) * 4) = v;
      }
    } else {
      float* dst = outp + (long)nt * HM32 + (m0 + wid * 32) * 32;
#pragma unroll
      for (int i = 0; i < 4; ++i) {
        float4 v = *(const float4*)&tb[wid][i * 256 + lane * 4];
        *(float4*)(dst + i * 256 + lane * 4) = v;
      }
    }
  }

#pragma unroll
  for (int nt = 0; nt < 4; ++nt) {
    ps[nt] += __shfl_xor(ps[nt], 32);
    pq[nt] += __shfl_xor(pq[nt], 32);
  }
  __syncthreads();
  if (hi == 0) {
#pragma unroll
    for (int nt = 0; nt < 4; ++nt) {
      atomicAdd(&csum[nt * 32 + ln], ps[nt]);
      atomicAdd(&csq[nt * 32 + ln], pq[nt]);
    }
  }
  __syncthreads();
  if (tid < 128) {
    atomicAdd(&stats[tid],       csum[tid]);
    atomicAdd(&stats[128 + tid], csq[tid]);
  }
}

// ---------------------------------------------------------------------------
// Fused Q/K/V/SKIP GEMM. A read once; weights cycled through a 2x32KB LDS
// double buffer (packed layout, conflict-free reads). Next-w global loads
// issue BEFORE the current-w MFMA block so the MFMA stream covers L2 latency.
// All outputs head-major bf16 via per-wave LDS bounce stores.
// ---------------------------------------------------------------------------
__global__ __launch_bounds__(256, 2) void gemm_qkvs(
    const float* __restrict__ A, const ushort* __restrict__ wbase,
    ushort* __restrict__ o0, ushort* __restrict__ o1,
    ushort* __restrict__ o2, ushort* __restrict__ o3,
    float* __restrict__ st0, float* __restrict__ st1,
    float* __restrict__ st2, float* __restrict__ st3)
{
  __shared__ ushort wbuf[2][16384];      // 64 KB weight dbuf
  __shared__ ushort qtb[4][1024];        // 8 KB per-wave bounce
  __shared__ float csum[4][128], csq[4][128];   // 4 KB
  const int tid = threadIdx.x;
  const int lane = tid & 63, wid = tid >> 6;
  const int hi = lane >> 5, ln = lane & 31;
  const long m0 = (long)blockIdx.x * 128;
  const long arow = m0 + wid * 32 + ln;

  if (tid < 128) {
#pragma unroll
    for (int w = 0; w < 4; ++w) { csum[w][tid] = 0.f; csq[w][tid] = 0.f; }
  }

  short8v afr[8];
  {
    const float* ar = A + arow * DIM + hi * 8;
#pragma unroll
    for (int kt = 0; kt < 8; ++kt) {
      float4 a0 = *(const float4*)(ar + kt * 16);
      float4 a1 = *(const float4*)(ar + kt * 16 + 4);
      short8v v;
      v[0] = (short)f2bf(a0.x); v[1] = (short)f2bf(a0.y);
      v[2] = (short)f2bf(a0.z); v[3] = (short)f2bf(a0.w);
      v[4] = (short)f2bf(a1.x); v[5] = (short)f2bf(a1.y);
      v[6] = (short)f2bf(a1.z); v[7] = (short)f2bf(a1.w);
      afr[kt] = v;
    }
  }

  // stage w=0
#pragma unroll
  for (int i = 0; i < 8; ++i)
    ((short8v*)wbuf[0])[i * 256 + tid] = ((const short8v*)wbase)[i * 256 + tid];

  float ps[4][4], pq[4][4];
#pragma unroll
  for (int w = 0; w < 4; ++w)
#pragma unroll
    for (int nt = 0; nt < 4; ++nt) { ps[w][nt] = 0.f; pq[w][nt] = 0.f; }

  __syncthreads();

#pragma unroll
  for (int w = 0; w < 4; ++w) {
    // prefetch next weight matrix into registers (issues before MFMA block)
    short8v nw[8];
    if (w < 3) {
      const int nxt = (w + 1 == 3) ? 4 : (w + 1);   // q,k,v,skip -> 0,1,2,4
      const short8v* src = (const short8v*)(wbase + nxt * 16384);
#pragma unroll
      for (int i = 0; i < 8; ++i) nw[i] = src[i * 256 + tid];
    }

    const ushort* wt = wbuf[w & 1];
    f32x16 acc[4];
#pragma unroll
    for (int nt = 0; nt < 4; ++nt)
#pragma unroll
      for (int r = 0; r < 16; ++r) acc[nt][r] = 0.f;
#pragma unroll
    for (int kt = 0; kt < 8; ++kt) {
      const ushort* wb = wt + (kt * 2 + hi) * 1024 + ln * 8;
#pragma unroll
      for (int nt = 0; nt < 4; ++nt) {
        short8v b = *(const short8v*)(wb + nt * 256);
        acc[nt] = __builtin_amdgcn_mfma_f32_32x32x16_bf16(afr[kt], b, acc[nt], 0, 0, 0);
      }
    }

    // write prefetched weights into the other buffer
    if (w < 3) {
      short8v* dst = (short8v*)wbuf[(w + 1) & 1];
#pragma unroll
      for (int i = 0; i < 8; ++i) dst[i * 256 + tid] = nw[i];
    }

    // bounce-store this w's output (head-major, 16B/lane coalesced)
    ushort* outp = (w == 0) ? o0 : (w == 1) ? o1 : (w == 2) ? o2 : o3;
#pragma unroll
    for (int nt = 0; nt < 4; ++nt) {
#pragma unroll
      for (int r = 0; r < 16; ++r) {
        const float v = acc[nt][r];
        ps[w][nt] += v; pq[w][nt] += v * v;
        const int row = (r & 3) + 8 * (r >> 2) + 4 * hi;
        qtb[wid][row * 32 + ln] = f2bf(v);
      }
      ushort* dst = outp + (long)nt * HM32 + (m0 + wid * 32) * 32;
      short8v v0 = *(const short8v*)&qtb[wid][lane * 8];
      short8v v1 = *(const short8v*)&qtb[wid][512 + lane * 8];
      *(short8v*)(dst + lane * 8)       = v0;
      *(short8v*)(dst + 512 + lane * 8) = v1;
    }
    __syncthreads();   // next buffer staged + all reads of current done
  }

  // stats: wave shuffle -> per-w LDS atomics -> one barrier -> global atomics
#pragma unroll
  for (int w = 0; w < 4; ++w) {
    float lps[4], lpq[4];
#pragma unroll
    for (int nt = 0; nt < 4; ++nt) {
      lps[nt] = ps[w][nt] + __shfl_xor(ps[w][nt], 32);
      lpq[nt] = pq[w][nt] + __shfl_xor(pq[w][nt], 32);
    }
    if (hi == 0) {
#pragma unroll
      for (int nt = 0; nt < 4; ++nt) {
        atomicAdd(&csum[w][nt * 32 + ln], lps[nt]);
        atomicAdd(&csq[w][nt * 32 + ln],  lpq[nt]);
      }
    }
  }
  __syncthreads();
  if (tid < 128) {
    atomicAdd(&st0[tid],       csum[0][tid]);
    atomicAdd(&st0[128 + tid], csq[0][tid]);
    atomicAdd(&st1[tid],       csum[1][tid]);
    atomicAdd(&st1[128 + tid], csq[1][tid]);
    atomicAdd(&st2[tid],       csum[2][tid]);
    atomicAdd(&st2[128 + tid], csq[2][tid]);
    atomicAdd(&st3[tid],       csum[3][tid]);
    atomicAdd(&st3[128 + tid], csq[3][tid]);
  }
}

// ---------------------------------------------------------------------------
// In-place BN apply for h (fp32).
// ---------------------------------------------------------------------------
__global__ __launch_bounds__(256) void bn_apply(
    float* __restrict__ x, const float* __restrict__ st,
    const float* __restrict__ g, const float* __restrict__ b)
{
  __shared__ float sc[128], bi[128];
  const int tid = threadIdx.x;
  if (tid < 128) {
    float mean = st[tid] * INV_M;
    float var  = st[128 + tid] * INV_M - mean * mean;
    float s = rsqrtf(var + EPSF) * g[tid];
    sc[tid] = s;
    bi[tid] = b[tid] - mean * s;
  }
  __syncthreads();
  const long total4 = (long)MTOT * DIM / 4;
  for (long i = (long)blockIdx.x * 256 + tid; i < total4; i += (long)gridDim.x * 256) {
    float4 vv = ((const float4*)x)[i];
    const int c = (int)((i * 4) & 127);
    vv.x = vv.x * sc[c + 0] + bi[c + 0];
    vv.y = vv.y * sc[c + 1] + bi[c + 1];
    vv.z = vv.z * sc[c + 2] + bi[c + 2];
    vv.w = vv.w * sc[c + 3] + bi[c + 3];
    ((float4*)x)[i] = vv;
  }
}

// ---------------------------------------------------------------------------
// Attention + fused LN(agg+h). One block per n; wave = head.
// S^T = mfma(K,Q) -> in-lane softmax; PV from D-regs; V BN folded via
// sum(P)=1; y = vs*o+vb0 + h (fp32); LN across waves via LDS reduce;
// out1 written FP32 IN-PLACE over h ([M][128]).
// ---------------------------------------------------------------------------
__global__ __launch_bounds__(256, 4) void attn_ln(
    const ushort* __restrict__ q, const ushort* __restrict__ k_in,
    const ushort* __restrict__ v_in,
    float* hbuf,                      // h in, out1 out (aliased on purpose)
    const uint4* __restrict__ mb,
    const float* __restrict__ qst, const float* __restrict__ kst, const float* __restrict__ vst,
    const float* __restrict__ qg, const float* __restrict__ qbb,
    const float* __restrict__ kg, const float* __restrict__ kbb,
    const float* __restrict__ vg, const float* __restrict__ vbb,
    const float* __restrict__ lng, const float* __restrict__ lnb)
{
  __shared__ ushort Vp[128 * 136];          // [c_global][slot(t)]
  __shared__ float qsc[128], qbi[128], ksc[128], kbi[128];
  __shared__ float reds[32][4], redq[32][4];
  __shared__ float2 rmv[32];

  const int tid = threadIdx.x;
  const int lane = tid & 63, hh = tid >> 6;
  const int hi = lane >> 5, ln = lane & 31;
  const int n = blockIdx.x;
  const long nb = (long)n * SEQ;            // global row base
  const long hbase = (long)hh * HM32 + nb * 32;

  if (tid < 128) {
    const int c = tid;
    float m, v, s;
    m = qst[c] * INV_M; v = qst[128 + c] * INV_M - m * m;
    s = rsqrtf(v + EPSF) * qg[c];  qsc[c] = s; qbi[c] = qbb[c] - m * s;
    m = kst[c] * INV_M; v = kst[128 + c] * INV_M - m * m;
    s = rsqrtf(v + EPSF) * kg[c];  ksc[c] = s; kbi[c] = kbb[c] - m * s;
  }
  const int cg = hh * 32 + ln;              // global output column
  float vs, vb0;
  {
    float m = vst[cg] * INV_M;
    float v = vst[128 + cg] * INV_M - m * m;
    vs = rsqrtf(v + EPSF) * vg[cg];
    vb0 = vbb[cg] - m * vs;
  }
  const float lgc = lng[cg], lbc = lnb[cg];

  // stage own head's V slice (dense 8KB) into permuted slots
#pragma unroll
  for (int it = 0; it < 8; ++it) {
    const int t = it * 16 + (lane >> 2);
    const int c0 = (lane & 3) * 8;
    short8v vv = *(const short8v*)(v_in + hbase + (long)t * 32 + c0);
    const int tl = t & 31;
    const int kt = tl >> 4;
    const int rem = tl & 15;
    const int slot = (t & 96) + (kt << 4) + ((rem >> 2) & 1) * 8 + ((rem & 3) | (((rem >> 3) & 1) << 2));
#pragma unroll
    for (int i = 0; i < 8; ++i) Vp[(hh * 32 + c0 + i) * 136 + slot] = (ushort)vv[i];
  }
  __syncthreads();

  // normalized K fragments, cached for all row-tiles
  short8v kfr[4][2];
#pragma unroll
  for (int nt = 0; nt < 4; ++nt)
#pragma unroll
    for (int kt = 0; kt < 2; ++kt) {
      short8v raw = *(const short8v*)(k_in + hbase + (long)(nt * 32 + ln) * 32 + kt * 16 + hi * 8);
      short8v f;
#pragma unroll
      for (int i = 0; i < 8; ++i) {
        const int c = hh * 32 + kt * 16 + hi * 8 + i;
        f[i] = (short)f2bf(bf2f((ushort)raw[i]) * ksc[c] + kbi[c]);
      }
      kfr[nt][kt] = f;
    }

  for (int mt = 0; mt < 4; ++mt) {
    // normalized Q fragments (B operand): col s = mt*32+ln
    short8v qfr[2];
#pragma unroll
    for (int kt = 0; kt < 2; ++kt) {
      short8v raw = *(const short8v*)(q + hbase + (long)(mt * 32 + ln) * 32 + kt * 16 + hi * 8);
      short8v f;
#pragma unroll
      for (int i = 0; i < 8; ++i) {
        const int c = hh * 32 + kt * 16 + hi * 8 + i;
        f[i] = (short)f2bf(bf2f((ushort)raw[i]) * qsc[c] + qbi[c]);
      }
      qfr[kt] = f;
    }

    f32x16 st[4];
#pragma unroll
    for (int nt = 0; nt < 4; ++nt)
#pragma unroll
      for (int r = 0; r < 16; ++r) st[nt][r] = 0.f;
#pragma unroll
    for (int nt = 0; nt < 4; ++nt) {
      st[nt] = __builtin_amdgcn_mfma_f32_32x32x16_bf16(kfr[nt][0], qfr[0], st[nt], 0, 0, 0);
      st[nt] = __builtin_amdgcn_mfma_f32_32x32x16_bf16(kfr[nt][1], qfr[1], st[nt], 0, 0, 0);
    }

    // mask + in-lane softmax (softmax(alpha*mask) semantics)
    const uint4 bw = mb[nb + mt * 32 + ln];
    float mx = -1e30f;
#pragma unroll
    for (int nt = 0; nt < 4; ++nt) {
      const uint word = (nt == 0) ? bw.x : (nt == 1) ? bw.y : (nt == 2) ? bw.z : bw.w;
#pragma unroll
      for (int r = 0; r < 16; ++r) {
        const int crow = (r & 3) + 8 * (r >> 2) + 4 * hi;
        st[nt][r] = ((word >> crow) & 1u) ? st[nt][r] : 0.f;
        mx = fmaxf(mx, st[nt][r]);
      }
    }
    mx = fmaxf(mx, __shfl_xor(mx, 32));
    float sum = 0.f;
#pragma unroll
    for (int nt = 0; nt < 4; ++nt)
#pragma unroll
      for (int r = 0; r < 16; ++r) {
        const float e = __expf(st[nt][r] - mx);
        st[nt][r] = e;
        sum += e;
      }
    sum += __shfl_xor(sum, 32);
    const float inv = 1.f / sum;

    // O = P · V_raw
    f32x16 o;
#pragma unroll
    for (int r = 0; r < 16; ++r) o[r] = 0.f;
#pragma unroll
    for (int nt = 0; nt < 4; ++nt) {
#pragma unroll
      for (int kt = 0; kt < 2; ++kt) {
        short8v pa;
#pragma unroll
        for (int j = 0; j < 8; ++j) pa[j] = (short)f2bf(st[nt][kt * 8 + j] * inv);
        short8v vb = *(const short8v*)&Vp[(long)cg * 136 + nt * 32 + kt * 16 + hi * 8];
        o = __builtin_amdgcn_mfma_f32_32x32x16_bf16(pa, vb, o, 0, 0, 0);
      }
    }

    // y = BN_v-folded agg + h  (fp32)
    float yv[16];
#pragma unroll
    for (int r = 0; r < 16; ++r) {
      const int sl = (r & 3) + 8 * (r >> 2) + 4 * hi;
      const float hval = hbuf[(nb + mt * 32 + sl) * DIM + cg];
      yv[r] = vs * o[r] + vb0 + hval;
    }

    // LN across full row: intra-half butterfly + cross-wave LDS reduce
#pragma unroll
    for (int r = 0; r < 16; ++r) {
      float s = yv[r], q2 = yv[r] * yv[r];
      s += __shfl_xor(s, 1);  q2 += __shfl_xor(q2, 1);
      s += __shfl_xor(s, 2);  q2 += __shfl_xor(q2, 2);
      s += __shfl_xor(s, 4);  q2 += __shfl_xor(q2, 4);
      s += __shfl_xor(s, 8);  q2 += __shfl_xor(q2, 8);
      s += __shfl_xor(s, 16); q2 += __shfl_xor(q2, 16);
      if (ln == 0) {
        const int sl = (r & 3) + 8 * (r >> 2) + 4 * hi;
        reds[sl][hh] = s; redq[sl][hh] = q2;
      }
    }
    __syncthreads();
    if (tid < 32) {
      const float s  = reds[tid][0] + reds[tid][1] + reds[tid][2] + reds[tid][3];
      const float q2 = redq[tid][0] + redq[tid][1] + redq[tid][2] + redq[tid][3];
      const float mean = s * (1.f / 128.f);
      const float var  = q2 * (1.f / 128.f) - mean * mean;
      rmv[tid] = make_float2(mean, rsqrtf(var + EPSF));
    }
    __syncthreads();
    // out1 fp32 in-place over h
#pragma unroll
    for (int r = 0; r < 16; ++r) {
      const int sl = (r & 3) + 8 * (r >> 2) + 4 * hi;
      const float2 mr = rmv[sl];
      hbuf[(nb + mt * 32 + sl) * DIM + cg] = (yv[r] - mr.x) * mr.y * lgc + lbc;
    }
  }
}

// ---------------------------------------------------------------------------
// h_new = LN(out1 + BN_ff(ff_raw)) + BN_skip(skip_raw).
// t1 (out1) fp32 [M][128]; ffr fp32 HEAD-MAJOR; skr bf16 HEAD-MAJOR.
// Non-final: out == t1 (in-place). FINAL: rows m=n*S -> d_out (N,128).
// ---------------------------------------------------------------------------
template <bool FINAL>
__global__ __launch_bounds__(256) void fuse2_k(
    const float* t1, const float* __restrict__ ffr, const ushort* __restrict__ skr,
    const float* __restrict__ fst, const float* __restrict__ sst,
    const float* __restrict__ fg, const float* __restrict__ fb,
    const float* __restrict__ sg, const float* __restrict__ sb,
    const float* __restrict__ lg, const float* __restrict__ lb,
    float* out)
{
  const int lane = threadIdx.x & 63;
  const int c = lane * 2;
  float fs0, fbias0, fs1, fbias1, ss0, sbias0, ss1, sbias1;
  {
    float m0 = fst[c] * INV_M;
    float v0 = fst[128 + c] * INV_M - m0 * m0;
    fs0 = rsqrtf(v0 + EPSF) * fg[c];       fbias0 = fb[c] - m0 * fs0;
    float m1 = fst[c + 1] * INV_M;
    float v1 = fst[128 + c + 1] * INV_M - m1 * m1;
    fs1 = rsqrtf(v1 + EPSF) * fg[c + 1];   fbias1 = fb[c + 1] - m1 * fs1;
    float n0 = sst[c] * INV_M;
    float w0 = sst[128 + c] * INV_M - n0 * n0;
    ss0 = rsqrtf(w0 + EPSF) * sg[c];       sbias0 = sb[c] - n0 * ss0;
    float n1 = sst[c + 1] * INV_M;
    float w1 = sst[128 + c + 1] * INV_M - n1 * n1;
    ss1 = rsqrtf(w1 + EPSF) * sg[c + 1];   sbias1 = sb[c + 1] - n1 * ss1;
  }
  const float lg0 = lg[c], lg1 = lg[c + 1], lb0 = lb[c], lb1 = lb[c + 1];
  const int wid = (blockIdx.x * 256 + threadIdx.x) >> 6;
  const int NW  = gridDim.x * 4;
  const int ROWS = FINAL ? NBATCH : MTOT;
  const long thm = (long)(c >> 5) * HM32;       // head region of cols c, c+1
  for (int r = wid; r < ROWS; r += NW) {
    const long m   = FINAL ? (long)r * SEQ : (long)r;
    const long off = m * DIM + c;
    const long hm  = thm + m * 32 + (c & 31);
    float2 tv = *(const float2*)(t1 + off);
    float2 fv = *(const float2*)(ffr + hm);
    uint sv = *(const uint*)(skr + hm);
    float s0 = bf2f((ushort)(sv & 0xFFFFu)), s1 = bf2f((ushort)(sv >> 16));
    float y0 = tv.x + fv.x * fs0 + fbias0;
    float y1 = tv.y + fv.y * fs1 + fbias1;
    float s = y0 + y1, sq = y0 * y0 + y1 * y1;
#pragma unroll
    for (int o = 32; o; o >>= 1) { s += __shfl_xor(s, o); sq += __shfl_xor(sq, o); }
    const float mean = s * (1.f / 128.f);
    const float var  = sq * (1.f / 128.f) - mean * mean;
    const float rs   = rsqrtf(var + EPSF);
    float o0 = (y0 - mean) * rs * lg0 + lb0 + (s0 * ss0 + sbias0);
    float o1 = (y1 - mean) * rs * lg1 + lb1 + (s1 * ss1 + sbias1);
    const long ooff = FINAL ? ((long)r * DIM + c) : off;
    *(float2*)(out + ooff) = make_float2(o0, o1);
  }
}

// ---------------------------------------------------------------------------
extern "C" void kernel_launch(void* const* d_in, const int* in_sizes, int n_in,
                              void* d_out, int out_size, void* d_ws, size_t ws_size,
                              hipStream_t stream)
{
  (void)in_sizes; (void)n_in; (void)out_size; (void)ws_size;
  const float* x    = (const float*)d_in[0];
  const float* mask = (const float*)d_in[1];
  const float* linW = (const float*)d_in[2];
  const float* ing  = (const float*)d_in[4];
  const float* inb  = (const float*)d_in[5];
  const float* qW   = (const float*)d_in[6];
  const float* qg   = (const float*)d_in[8];
  const float* qb   = (const float*)d_in[9];
  const float* kW   = (const float*)d_in[10];
  const float* kg   = (const float*)d_in[12];
  const float* kb   = (const float*)d_in[13];
  const float* vW   = (const float*)d_in[14];
  const float* vg   = (const float*)d_in[16];
  const float* vb   = (const float*)d_in[17];
  const float* lng  = (const float*)d_in[18];
  const float* lnb  = (const float*)d_in[19];
  const float* ffW  = (const float*)d_in[20];
  const float* ffg  = (const float*)d_in[22];
  const float* ffb  = (const float*)d_in[23];
  const float* skW  = (const float*)d_in[24];
  const float* skg  = (const float*)d_in[26];
  const float* skb  = (const float*)d_in[27];

  const long MD = (long)MTOT * DIM;
  float*  stats = (float*)d_ws;                 // 11*256 floats
  float*  h     = (float*)d_ws + 4096;          // fp32 [M][128]; also out1/h_next
  ushort* qbuf  = (ushort*)(h + MD);            // bf16 head-major q
  ushort* kbuf  = qbuf + MD;                    // bf16 head-major k
  ushort* vbuf  = kbuf + MD;                    // bf16 head-major v
  ushort* sbuf  = vbuf + MD;                    // bf16 head-major skip_raw
  uint4*  mbits = (uint4*)(sbuf + MD);          // 2 MB; total ~194 MB
  float*  ffbuf = (float*)qbuf;                 // fp32 head-major ff over dead q+k

  ushort* Wsw = (ushort*)d_out;                 // 352 KB of 512 KB; final
                                                // fuse2<true> overwrites all.
  hipMemsetAsync(stats, 0, 11 * 256 * sizeof(float), stream);

  WPtrs wp;
  wp.p[0] = linW;
  wp.p[1] = qW;            wp.p[2] = kW;            wp.p[3] = vW;
  wp.p[4] = ffW;           wp.p[5] = skW;
  wp.p[6] = qW + 16384;    wp.p[7] = kW + 16384;    wp.p[8] = vW + 16384;
  wp.p[9] = ffW + 16384;   wp.p[10] = skW + 16384;
  prep_w<<<88, 256, 0, stream>>>(wp, Wsw);
  pack_mask<<<512, 256, 0, stream>>>(mask, mbits);

  gemm_one<0><<<MTOT / 128, 256, 0, stream>>>(x, Wsw, h, stats);
  bn_apply<<<1024, 256, 0, stream>>>(h, stats, ing, inb);

  for (int l = 0; l < NLAYER; ++l) {
    const int poff = l * DIM;
    const ushort* wbase = Wsw + (1 + 5 * l) * 16384;
    float* stq = stats + (1 + 5 * l) * 256;
    float* stk = stats + (2 + 5 * l) * 256;
    float* stv = stats + (3 + 5 * l) * 256;
    float* stf = stats + (4 + 5 * l) * 256;
    float* sts = stats + (5 + 5 * l) * 256;

    gemm_qkvs<<<MTOT / 128, 256, 0, stream>>>(h, wbase, qbuf, kbuf, vbuf, sbuf,
                                              stq, stk, stv, sts);

    attn_ln<<<NBATCH, 256, 0, stream>>>(
        qbuf, kbuf, vbuf, h /* h in, out1 fp32 out (in-place) */, mbits,
        stq, stk, stv,
        qg + poff, qb + poff, kg + poff, kb + poff, vg + poff, vb + poff,
        lng + poff, lnb + poff);

    // ff_raw = gemm(out1); A fp32 row-major from h, out fp32 HEAD-MAJOR
    gemm_one<1><<<MTOT / 128, 256, 0, stream>>>(
        h, wbase + 3 * 16384, ffbuf, stf);

    if (l < NLAYER - 1) {
      fuse2_k<false><<<1024, 256, 0, stream>>>(
          h, ffbuf, sbuf, stf, sts,
          ffg + poff, ffb + poff, skg + poff, skb + poff,
          lng + poff, lnb + poff, h /* in-place */);
    } else {
      fuse2_k<true><<<64, 256, 0, stream>>>(
          h, ffbuf, sbuf, stf, sts,
          ffg + poff, ffb + poff, skg + poff, skb + poff,
          lng + poff, lnb + poff, (float*)d_out);
    }
  }
}